// Round 1
// baseline (1230.526 us; speedup 1.0000x reference)
//
#include <hip/hip_runtime.h>

#define B_ 2
#define L_ 2048
#define D_ 2048
#define H_ 8
#define HD_ 256
#define FD_ 64
#define F_ 128          // 2*FD
#define NC_ 32          // L/CHUNK
#define M_ (B_*L_)      // 4096
#define SCALE_Q 0.08838834764831845f   // 128^-0.5

#define FMA4(a_, s_, v_) { (a_).x += (s_)*(v_).x; (a_).y += (s_)*(v_).y; \
                           (a_).z += (s_)*(v_).z; (a_).w += (s_)*(v_).w; }

// ---------------------------------------------------------------------------
// fp32 SGEMM body: 128x128 tile, BK=16, 256 threads, 8x8 per thread split as
// 2x2 blocks of 4x4 (conflict-free b128 LDS reads: stride-16B lane pattern).
// ---------------------------------------------------------------------------
__device__ __forceinline__ void sgemm_body(const float* __restrict__ A,
                                           const float* __restrict__ Bw,
                                           float* __restrict__ C,
                                           int N, int K, int bm, int bn) {
  __shared__ __align__(16) float As[16][132];   // [k][m], transposed A tile
  __shared__ __align__(16) float Bs[16][132];   // [k][n]
  const int t = threadIdx.x;
  const int tx = t & 15, ty = t >> 4;
  const float* Ablk = A + (size_t)bm * 128 * K;
  const float* Bblk = Bw + (size_t)bn * 128;
  float4 acc[2][4][2];
  #pragma unroll
  for (int im = 0; im < 2; ++im)
    #pragma unroll
    for (int i = 0; i < 4; ++i)
      #pragma unroll
      for (int jm = 0; jm < 2; ++jm)
        acc[im][i][jm] = make_float4(0.f, 0.f, 0.f, 0.f);

  const int ar = t >> 2, ac = (t & 3) << 2;   // A tile: row ar/ar+64, cols ac..ac+3
  const int br = t >> 5, bc = (t & 31) << 2;  // B tile: row br/br+8, cols bc..bc+3

  for (int k0 = 0; k0 < K; k0 += 16) {
    float4 a0 = *(const float4*)(Ablk + (size_t)ar * K + k0 + ac);
    float4 a1 = *(const float4*)(Ablk + (size_t)(ar + 64) * K + k0 + ac);
    float4 b0 = *(const float4*)(Bblk + (size_t)(k0 + br) * N + bc);
    float4 b1 = *(const float4*)(Bblk + (size_t)(k0 + br + 8) * N + bc);
    __syncthreads();
    As[ac+0][ar] = a0.x; As[ac+1][ar] = a0.y; As[ac+2][ar] = a0.z; As[ac+3][ar] = a0.w;
    As[ac+0][ar+64] = a1.x; As[ac+1][ar+64] = a1.y; As[ac+2][ar+64] = a1.z; As[ac+3][ar+64] = a1.w;
    *(float4*)&Bs[br][bc] = b0;
    *(float4*)&Bs[br+8][bc] = b1;
    __syncthreads();
    #pragma unroll
    for (int kk = 0; kk < 16; ++kk) {
      float4 av0 = *(const float4*)&As[kk][ty*4];
      float4 av1 = *(const float4*)&As[kk][ty*4 + 64];
      float4 bv0 = *(const float4*)&Bs[kk][tx*4];
      float4 bv1 = *(const float4*)&Bs[kk][tx*4 + 64];
      float a_[2][4] = {{av0.x, av0.y, av0.z, av0.w}, {av1.x, av1.y, av1.z, av1.w}};
      float4 b_[2] = {bv0, bv1};
      #pragma unroll
      for (int im = 0; im < 2; ++im)
        #pragma unroll
        for (int i = 0; i < 4; ++i)
          #pragma unroll
          for (int jm = 0; jm < 2; ++jm)
            FMA4(acc[im][i][jm], a_[im][i], b_[jm]);
    }
  }
  #pragma unroll
  for (int im = 0; im < 2; ++im)
    #pragma unroll
    for (int i = 0; i < 4; ++i) {
      size_t row = (size_t)bm * 128 + im * 64 + ty * 4 + i;
      #pragma unroll
      for (int jm = 0; jm < 2; ++jm)
        *(float4*)(C + row * N + (size_t)bn * 128 + jm * 64 + tx * 4) = acc[im][i][jm];
    }
}

// Fused QKV projection: grid.x selects which weight/output a column-tile uses.
__global__ __launch_bounds__(256)
void sgemm_qkv(const float* __restrict__ A, const float* __restrict__ Wq,
               const float* __restrict__ Wk, const float* __restrict__ Wv,
               float* __restrict__ Cq, float* __restrict__ Ck, float* __restrict__ Cv) {
  int bn = blockIdx.x, bm = blockIdx.y;
  const float* Bw; float* C; int N; int bc;
  if (bn < 16)      { Bw = Wq; C = Cq; N = 2048; bc = bn; }
  else if (bn < 18) { Bw = Wk; C = Ck; N = 256;  bc = bn - 16; }
  else              { Bw = Wv; C = Cv; N = 256;  bc = bn - 18; }
  sgemm_body(A, Bw, C, N, D_, bm, bc);
}

__global__ __launch_bounds__(256)
void sgemm_kernel(const float* __restrict__ A, const float* __restrict__ Bw,
                  float* __restrict__ C, int N, int K) {
  sgemm_body(A, Bw, C, N, K, blockIdx.y, blockIdx.x);
}

// ---------------------------------------------------------------------------
// In-place RoPE on (B,L,heads,HD): pair (d, d+128) per thread.
// ---------------------------------------------------------------------------
__global__ __launch_bounds__(256)
void rope_kernel(float* __restrict__ x, const float* __restrict__ cosb,
                 const float* __restrict__ sinb, int heads) {
  int idx = blockIdx.x * 256 + threadIdx.x;        // over B*L*heads*128
  int d = idx & 127;
  int rest = idx >> 7;
  int h = rest % heads;
  int bl = rest / heads;                           // b*L + l
  int l = bl & (L_ - 1);
  size_t base = ((size_t)bl * heads + h) * HD_;
  float c = cosb[l * 128 + d], s = sinb[l * 128 + d];
  float x1 = x[base + d], x2 = x[base + 128 + d];
  x[base + d]       = x1 * c - x2 * s;
  x[base + 128 + d] = x1 * s + x2 * c;
}

__device__ __forceinline__ float wave_max64(float v) {
  #pragma unroll
  for (int off = 32; off > 0; off >>= 1) v = fmaxf(v, __shfl_xor(v, off, 64));
  return v;
}
__device__ __forceinline__ float wave_sum64(float v) {
  #pragma unroll
  for (int off = 32; off > 0; off >>= 1) v += __shfl_xor(v, off, 64);
  return v;
}

// ---------------------------------------------------------------------------
// Hedgehog feature map: out[b,h,l,0:64]=softmax part exp(p), [64:128]=exp(-p).
// One wave handles 4 consecutive l for one (b,h); lane = feature f (0..63).
// ---------------------------------------------------------------------------
__global__ __launch_bounds__(256)
void hedgehog_kernel(const float* __restrict__ x, const float* __restrict__ fm,
                     float* __restrict__ out, int nh_in) {
  __shared__ __align__(16) float rows[4][4][256];
  int wave = threadIdx.x >> 6, lane = threadIdx.x & 63;
  int g = blockIdx.x * 4 + wave;                   // over B*H*(L/4)
  int l4 = g & (L_/4 - 1);
  int bh = g / (L_/4);
  int h = bh & 7, b = bh >> 3;
  int l0 = l4 * 4;
  size_t rstride = (nh_in == 1) ? (size_t)HD_ : (size_t)H_ * HD_;
  const float* xrow = (nh_in == 1)
      ? x + (size_t)(b * L_ + l0) * HD_
      : x + ((size_t)(b * L_ + l0) * H_ + h) * HD_;
  #pragma unroll
  for (int r = 0; r < 4; ++r)
    *(float4*)&rows[wave][r][lane * 4] = *(const float4*)(xrow + r * rstride + lane * 4);
  __syncthreads();

  const float* fmh = fm + (size_t)h * HD_ * FD_;
  float p0 = 0.f, p1 = 0.f, p2 = 0.f, p3 = 0.f;
  for (int dd = 0; dd < HD_; dd += 4) {
    float w0 = fmh[(dd + 0) * FD_ + lane];
    float w1 = fmh[(dd + 1) * FD_ + lane];
    float w2 = fmh[(dd + 2) * FD_ + lane];
    float w3 = fmh[(dd + 3) * FD_ + lane];
    float4 r0 = *(const float4*)&rows[wave][0][dd];
    float4 r1 = *(const float4*)&rows[wave][1][dd];
    float4 r2 = *(const float4*)&rows[wave][2][dd];
    float4 r3 = *(const float4*)&rows[wave][3][dd];
    p0 += r0.x * w0 + r0.y * w1 + r0.z * w2 + r0.w * w3;
    p1 += r1.x * w0 + r1.y * w1 + r1.z * w2 + r1.w * w3;
    p2 += r2.x * w0 + r2.y * w1 + r2.z * w2 + r2.w * w3;
    p3 += r3.x * w0 + r3.y * w1 + r3.z * w2 + r3.w * w3;
  }
  float p[4] = {p0, p1, p2, p3};
  #pragma unroll
  for (int r = 0; r < 4; ++r) {
    float m = wave_max64(fabsf(p[r]));             // max over concat([p,-p])
    float e1 = __expf(p[r] - m);
    float e2 = __expf(-p[r] - m);
    float z = wave_sum64(e1 + e2);
    float inv = 1.0f / z;
    size_t base = ((size_t)bh * L_ + l0 + r) * F_;
    out[base + lane]      = e1 * inv;
    out[base + 64 + lane] = e2 * inv;
  }
}

// ---------------------------------------------------------------------------
// Phase A: per-chunk kv_n[f][d] = sum_{j in chunk} kf[j][f] * v[j][d]
// block = (b,h,n), 256 threads; thread tile 8f x 4d, 4 passes over f.
// ---------------------------------------------------------------------------
__global__ __launch_bounds__(256)
void chunk_kv_kernel(const float* __restrict__ kf, const float* __restrict__ v,
                     float* __restrict__ kvc) {
  __shared__ __align__(16) float kfs[64][128];
  int n = blockIdx.x & (NC_ - 1), bh = blockIdx.x >> 5;
  int b = bh >> 3;
  const float* kfp = kf + ((size_t)bh * L_ + (size_t)n * 64) * F_;
  int t = threadIdx.x;
  #pragma unroll
  for (int it = 0; it < 8; ++it) {
    int flat = t * 4 + it * 1024;
    *(float4*)&kfs[flat >> 7][flat & 127] = *(const float4*)(kfp + flat);
  }
  __syncthreads();
  int dg = t & 63;                   // d = dg*4
  int fg = t >> 6;                   // 0..3
  const float* vp = v + (size_t)(b * L_ + n * 64) * HD_ + dg * 4;
  float* outp = kvc + (size_t)blockIdx.x * (F_ * HD_) + dg * 4;
  #pragma unroll
  for (int pass = 0; pass < 4; ++pass) {
    int f0 = fg * 8 + pass * 32;
    float4 acc[8];
    #pragma unroll
    for (int i = 0; i < 8; ++i) acc[i] = make_float4(0.f, 0.f, 0.f, 0.f);
    for (int j = 0; j < 64; ++j) {
      float4 vv = *(const float4*)(vp + (size_t)j * HD_);
      float4 ka = *(const float4*)&kfs[j][f0];
      float4 kb = *(const float4*)&kfs[j][f0 + 4];
      FMA4(acc[0], ka.x, vv); FMA4(acc[1], ka.y, vv);
      FMA4(acc[2], ka.z, vv); FMA4(acc[3], ka.w, vv);
      FMA4(acc[4], kb.x, vv); FMA4(acc[5], kb.y, vv);
      FMA4(acc[6], kb.z, vv); FMA4(acc[7], kb.w, vv);
    }
    #pragma unroll
    for (int ff = 0; ff < 8; ++ff)
      *(float4*)(outp + (size_t)(f0 + ff) * HD_) = acc[ff];
  }
}

// Phase B: exclusive prefix-sum over the 32 chunks, per (b,h,f,d) column.
__global__ __launch_bounds__(256)
void chunk_scan_kernel(float* __restrict__ kvc) {
  size_t c = (size_t)blockIdx.x * 256 + threadIdx.x;   // over B*H * 32768
  size_t bh = c >> 15;
  size_t fd = c & 32767;
  float* p = kvc + bh * ((size_t)NC_ * F_ * HD_) + fd;
  float run = 0.f;
  #pragma unroll
  for (int n = 0; n < NC_; ++n) {
    float val = p[(size_t)n * (F_ * HD_)];
    p[(size_t)n * (F_ * HD_)] = run;
    run += val;
  }
}

// ---------------------------------------------------------------------------
// Phase C: out[i][d] = qs[i]·kv_cum[:,d] + sum_{j<=i} (qs[i]·kf[j]) v[j][d]
// block = (b,h,n), 512 threads. Transposed LDS tiles (pad 68) for
// conflict-free b128 reads; s computed by threads 0..255 (4x4 tile each).
// ---------------------------------------------------------------------------
__global__ __launch_bounds__(512)
void chunk_attn_kernel(const float* __restrict__ qf, const float* __restrict__ kf,
                       const float* __restrict__ v, const float* __restrict__ kvc,
                       float* __restrict__ o) {
  __shared__ __align__(16) float qsT[128][68];   // [f][i], scaled q features
  __shared__ __align__(16) float ksT[128][68];   // [f][j]
  __shared__ __align__(16) float ssT[64][68];    // [j][i], masked scores
  int n = blockIdx.x & (NC_ - 1), bh = blockIdx.x >> 5;
  int h = bh & 7, b = bh >> 3;
  int t = threadIdx.x;
  const float* qp = qf + ((size_t)bh * L_ + (size_t)n * 64) * F_;
  const float* kp = kf + ((size_t)bh * L_ + (size_t)n * 64) * F_;
  #pragma unroll
  for (int it = 0; it < 4; ++it) {
    int flat = t * 4 + it * 2048;                // 8192 elems per matrix
    int j = flat >> 7, f = flat & 127;
    float4 qv = *(const float4*)(qp + flat);
    qsT[f + 0][j] = qv.x * SCALE_Q; qsT[f + 1][j] = qv.y * SCALE_Q;
    qsT[f + 2][j] = qv.z * SCALE_Q; qsT[f + 3][j] = qv.w * SCALE_Q;
    float4 kv_ = *(const float4*)(kp + flat);
    ksT[f + 0][j] = kv_.x; ksT[f + 1][j] = kv_.y;
    ksT[f + 2][j] = kv_.z; ksT[f + 3][j] = kv_.w;
  }
  __syncthreads();

  if (t < 256) {
    int j4 = (t & 15) * 4, i4 = (t >> 4) * 4;
    float4 accs[4];
    #pragma unroll
    for (int i = 0; i < 4; ++i) accs[i] = make_float4(0.f, 0.f, 0.f, 0.f);
    for (int f = 0; f < F_; ++f) {
      float4 a4 = *(const float4*)&qsT[f][i4];
      float4 b4 = *(const float4*)&ksT[f][j4];
      FMA4(accs[0], a4.x, b4); FMA4(accs[1], a4.y, b4);
      FMA4(accs[2], a4.z, b4); FMA4(accs[3], a4.w, b4);
    }
    #pragma unroll
    for (int ii = 0; ii < 4; ++ii) {
      float sv[4] = {accs[ii].x, accs[ii].y, accs[ii].z, accs[ii].w};
      #pragma unroll
      for (int jj = 0; jj < 4; ++jj) {
        int i = i4 + ii, j = j4 + jj;
        ssT[j][i] = (j <= i) ? sv[jj] : 0.f;     // causal mask (diag kept)
      }
    }
  }
  __syncthreads();

  int dg = t & 31, ig = t >> 5;                  // ig 0..15
  int i4 = ig * 4;
  const float* kvp = kvc + (size_t)blockIdx.x * (F_ * HD_);
  const float* vp = v + (size_t)(b * L_ + n * 64) * HD_;
  float* op = o + ((size_t)(b * L_ + n * 64) * H_ + h) * HD_;
  #pragma unroll
  for (int pass = 0; pass < 2; ++pass) {
    int d0 = dg * 4 + pass * 128;
    float4 acc[4];
    #pragma unroll
    for (int i = 0; i < 4; ++i) acc[i] = make_float4(0.f, 0.f, 0.f, 0.f);
    for (int f = 0; f < F_; ++f) {               // inter-chunk: qs @ kv_cum
      float4 kvv = *(const float4*)(kvp + (size_t)f * HD_ + d0);
      float4 a4 = *(const float4*)&qsT[f][i4];
      FMA4(acc[0], a4.x, kvv); FMA4(acc[1], a4.y, kvv);
      FMA4(acc[2], a4.z, kvv); FMA4(acc[3], a4.w, kvv);
    }
    for (int j = 0; j < 64; ++j) {               // intra-chunk: s @ v
      float4 vv = *(const float4*)(vp + (size_t)j * HD_ + d0);
      float4 s4 = *(const float4*)&ssT[j][i4];
      FMA4(acc[0], s4.x, vv); FMA4(acc[1], s4.y, vv);
      FMA4(acc[2], s4.z, vv); FMA4(acc[3], s4.w, vv);
    }
    #pragma unroll
    for (int ii = 0; ii < 4; ++ii)
      *(float4*)(op + (size_t)(i4 + ii) * (H_ * HD_) + d0) = acc[ii];
  }
}

// ---------------------------------------------------------------------------
extern "C" void kernel_launch(void* const* d_in, const int* in_sizes, int n_in,
                              void* d_out, int out_size, void* d_ws, size_t ws_size,
                              hipStream_t stream) {
  const float* hs   = (const float*)d_in[0];
  const float* fcos = (const float*)d_in[1];
  const float* fsin = (const float*)d_in[2];
  // d_in[3] = mask (all ones, unused by the reference computation)
  const float* Wq  = (const float*)d_in[4];
  const float* Wk  = (const float*)d_in[5];
  const float* Wv  = (const float*)d_in[6];
  const float* Wo  = (const float*)d_in[7];
  const float* fmq = (const float*)d_in[8];
  const float* fmk = (const float*)d_in[9];
  float* out = (float*)d_out;

  float* ws = (float*)d_ws;
  float* q  = ws;                                   // M*2048 (reused as o)
  float* k  = q  + (size_t)M_ * 2048;               // M*256
  float* v  = k  + (size_t)M_ * 256;                // M*256
  float* qf = v  + (size_t)M_ * 256;                // B*H*L*128
  float* kf = qf + (size_t)B_ * H_ * L_ * F_;       // B*H*L*128
  float* kv = kf + (size_t)B_ * H_ * L_ * F_;       // B*H*NC*128*256

  // 1) QKV projections (fused: 16 q-tiles + 2 k-tiles + 2 v-tiles per row-block)
  sgemm_qkv<<<dim3(20, 32), 256, 0, stream>>>(hs, Wq, Wk, Wv, q, k, v);
  // 2) RoPE in place
  rope_kernel<<<(M_ * H_ * 128) / 256, 256, 0, stream>>>(q, fcos, fsin, H_);
  rope_kernel<<<(M_ * 1 * 128) / 256, 256, 0, stream>>>(k, fcos, fsin, 1);
  // 3) Hedgehog feature maps
  hedgehog_kernel<<<(B_ * H_ * L_) / 16, 256, 0, stream>>>(q, fmq, qf, H_);
  hedgehog_kernel<<<(B_ * H_ * L_) / 16, 256, 0, stream>>>(k, fmk, kf, 1);
  // 4) Per-chunk k^T v outer products, then exclusive scan over chunks
  chunk_kv_kernel<<<B_ * H_ * NC_, 256, 0, stream>>>(kf, v, kv);
  chunk_scan_kernel<<<(B_ * H_ * F_ * HD_) / 256, 256, 0, stream>>>(kv);
  // 5) inter + intra chunk attention -> o (reuses q buffer)
  chunk_attn_kernel<<<B_ * H_ * NC_, 512, 0, stream>>>(qf, kf, v, kv, q);
  // 6) Output projection
  sgemm_kernel<<<dim3(16, 32), 256, 0, stream>>>(q, Wo, out, D_, H_ * HD_);
}

// Round 2
// 654.514 us; speedup vs baseline: 1.8801x; 1.8801x over previous
//
#include <hip/hip_runtime.h>

#define B_ 2
#define L_ 2048
#define D_ 2048
#define H_ 8
#define HD_ 256
#define FD_ 64
#define F_ 128          // 2*FD
#define NC_ 32          // L/CHUNK
#define M_ (B_*L_)      // 4096
#define SCALE_Q 0.08838834764831845f   // 128^-0.5

typedef unsigned short u16;
typedef __attribute__((ext_vector_type(8))) short bf16x8;
typedef __attribute__((ext_vector_type(4))) float f32x4;

#define FMA4(a_, s_, v_) { (a_).x += (s_)*(v_).x; (a_).y += (s_)*(v_).y; \
                           (a_).z += (s_)*(v_).z; (a_).w += (s_)*(v_).w; }

// ---------------------------------------------------------------------------
// bf16 split helpers (round-to-nearest-even)
// ---------------------------------------------------------------------------
__device__ __forceinline__ u16 bf16_rne(float x) {
  unsigned u = __float_as_uint(x);
  return (u16)((u + 0x7fffu + ((u >> 16) & 1u)) >> 16);
}
__device__ __forceinline__ void bf16_split(float x, u16& h, u16& l) {
  unsigned u = __float_as_uint(x);
  unsigned hb = (u + 0x7fffu + ((u >> 16) & 1u)) >> 16;
  h = (u16)hb;
  float hf = __uint_as_float(hb << 16);
  l = bf16_rne(x - hf);
}

// Split a contiguous fp32 array into bf16 hi/lo arrays. 4 elems/thread.
__global__ __launch_bounds__(256)
void split_kernel(const float* __restrict__ x, u16* __restrict__ h,
                  u16* __restrict__ l) {
  int i = (blockIdx.x * 256 + threadIdx.x) * 4;
  float4 vv = *(const float4*)(x + i);
  ushort4 hv, lv;
  bf16_split(vv.x, hv.x, lv.x);
  bf16_split(vv.y, hv.y, lv.y);
  bf16_split(vv.z, hv.z, lv.z);
  bf16_split(vv.w, hv.w, lv.w);
  *(ushort4*)(h + i) = hv;
  *(ushort4*)(l + i) = lv;
}

// Transpose W[K][N] -> T[N][K] with bf16 hi/lo split. 32x32 tiles.
__global__ __launch_bounds__(256)
void transpose_split(const float* __restrict__ W, u16* __restrict__ Th,
                     u16* __restrict__ Tl, int K, int N) {
  __shared__ float tile[32][33];
  int n0 = blockIdx.x * 32, k0 = blockIdx.y * 32;
  int tx = threadIdx.x & 31, ty = threadIdx.x >> 5;   // ty 0..7
  #pragma unroll
  for (int i = 0; i < 4; ++i)
    tile[ty + i * 8][tx] = W[(size_t)(k0 + ty + i * 8) * N + n0 + tx];
  __syncthreads();
  #pragma unroll
  for (int i = 0; i < 4; ++i) {
    float x = tile[tx][ty + i * 8];     // W[k0+tx][n0+ty+i*8]
    u16 hb, lb; bf16_split(x, hb, lb);
    size_t idx = (size_t)(n0 + ty + i * 8) * K + k0 + tx;
    Th[idx] = hb; Tl[idx] = lb;
  }
}

// ---------------------------------------------------------------------------
// Split-bf16 MFMA GEMM: C(fp32) = (Ah+Al)(Bh+Bl) ~= AhBh + AhBl + AlBh
// A: [M][K] row-major bf16-bits; B: B^T [N][K] row-major bf16-bits.
// 128x128 tile, BK=32, 256 threads (4 waves, each wave 64x64 = 4x4 MFMA tiles)
// LDS rows padded 32->40 bf16 (2-way max on frag reads = free).
// ---------------------------------------------------------------------------
__device__ __forceinline__ void mfma_gemm_body(
    const u16* __restrict__ Ah, const u16* __restrict__ Al,
    const u16* __restrict__ Bh, const u16* __restrict__ Bl,
    float* __restrict__ C, int N, int K, int bm, int bn) {
  __shared__ __align__(16) u16 Ahs[128][40];
  __shared__ __align__(16) u16 Als[128][40];
  __shared__ __align__(16) u16 Bhs[128][40];
  __shared__ __align__(16) u16 Bls[128][40];
  const int t = threadIdx.x;
  const int lane = t & 63, wave = t >> 6;
  const int wm = wave >> 1, wn = wave & 1;
  // staging: 2 16B-chunks per matrix per thread (512 chunks of 8 bf16)
  const int c0 = t * 2, c1 = c0 + 1;
  const int r0 = c0 >> 2, o0 = (c0 & 3) * 8;
  const int r1 = c1 >> 2, o1 = (c1 & 3) * 8;
  const u16* Ahp = Ah + (size_t)(bm * 128) * K;
  const u16* Alp = Al + (size_t)(bm * 128) * K;
  const u16* Bhp = Bh + (size_t)(bn * 128) * K;
  const u16* Blp = Bl + (size_t)(bn * 128) * K;
  const int fr = lane & 15, fq = (lane >> 4) * 8;   // fragment row / k-offset

  f32x4 acc[4][4];
  #pragma unroll
  for (int a = 0; a < 4; ++a)
    #pragma unroll
    for (int b2 = 0; b2 < 4; ++b2) acc[a][b2] = {0.f, 0.f, 0.f, 0.f};

  for (int k0 = 0; k0 < K; k0 += 32) {
    bf16x8 sa0 = *(const bf16x8*)(Ahp + (size_t)r0 * K + k0 + o0);
    bf16x8 sa1 = *(const bf16x8*)(Ahp + (size_t)r1 * K + k0 + o1);
    bf16x8 sl0 = *(const bf16x8*)(Alp + (size_t)r0 * K + k0 + o0);
    bf16x8 sl1 = *(const bf16x8*)(Alp + (size_t)r1 * K + k0 + o1);
    bf16x8 sb0 = *(const bf16x8*)(Bhp + (size_t)r0 * K + k0 + o0);
    bf16x8 sb1 = *(const bf16x8*)(Bhp + (size_t)r1 * K + k0 + o1);
    bf16x8 sm0 = *(const bf16x8*)(Blp + (size_t)r0 * K + k0 + o0);
    bf16x8 sm1 = *(const bf16x8*)(Blp + (size_t)r1 * K + k0 + o1);
    __syncthreads();
    *(bf16x8*)&Ahs[r0][o0] = sa0; *(bf16x8*)&Ahs[r1][o1] = sa1;
    *(bf16x8*)&Als[r0][o0] = sl0; *(bf16x8*)&Als[r1][o1] = sl1;
    *(bf16x8*)&Bhs[r0][o0] = sb0; *(bf16x8*)&Bhs[r1][o1] = sb1;
    *(bf16x8*)&Bls[r0][o0] = sm0; *(bf16x8*)&Bls[r1][o1] = sm1;
    __syncthreads();

    bf16x8 fa[4], fb[4], fx[4];
    #pragma unroll
    for (int mt = 0; mt < 4; ++mt)
      fa[mt] = *(const bf16x8*)&Ahs[wm * 64 + mt * 16 + fr][fq];
    #pragma unroll
    for (int nt = 0; nt < 4; ++nt)
      fb[nt] = *(const bf16x8*)&Bhs[wn * 64 + nt * 16 + fr][fq];
    #pragma unroll
    for (int mt = 0; mt < 4; ++mt)
      #pragma unroll
      for (int nt = 0; nt < 4; ++nt)
        acc[mt][nt] = __builtin_amdgcn_mfma_f32_16x16x32_bf16(fa[mt], fb[nt], acc[mt][nt], 0, 0, 0);
    #pragma unroll
    for (int nt = 0; nt < 4; ++nt)
      fx[nt] = *(const bf16x8*)&Bls[wn * 64 + nt * 16 + fr][fq];
    #pragma unroll
    for (int mt = 0; mt < 4; ++mt)
      #pragma unroll
      for (int nt = 0; nt < 4; ++nt)
        acc[mt][nt] = __builtin_amdgcn_mfma_f32_16x16x32_bf16(fa[mt], fx[nt], acc[mt][nt], 0, 0, 0);
    #pragma unroll
    for (int mt = 0; mt < 4; ++mt)
      fa[mt] = *(const bf16x8*)&Als[wm * 64 + mt * 16 + fr][fq];   // reuse regs
    #pragma unroll
    for (int mt = 0; mt < 4; ++mt)
      #pragma unroll
      for (int nt = 0; nt < 4; ++nt)
        acc[mt][nt] = __builtin_amdgcn_mfma_f32_16x16x32_bf16(fa[mt], fb[nt], acc[mt][nt], 0, 0, 0);
  }

  // Epilogue: C/D layout col=lane&15, row=(lane>>4)*4+i
  float* Cp = C + (size_t)(bm * 128 + wm * 64) * N + bn * 128 + wn * 64;
  const int rq = (lane >> 4) * 4;
  #pragma unroll
  for (int mt = 0; mt < 4; ++mt)
    #pragma unroll
    for (int nt = 0; nt < 4; ++nt) {
      #pragma unroll
      for (int i = 0; i < 4; ++i)
        Cp[(size_t)(mt * 16 + rq + i) * N + nt * 16 + fr] = acc[mt][nt][i];
    }
}

__global__ __launch_bounds__(256)
void mfma_qkv(const u16* __restrict__ hsH, const u16* __restrict__ hsL,
              const u16* __restrict__ WqTh, const u16* __restrict__ WqTl,
              const u16* __restrict__ WkTh, const u16* __restrict__ WkTl,
              const u16* __restrict__ WvTh, const u16* __restrict__ WvTl,
              float* __restrict__ q, float* __restrict__ k, float* __restrict__ v) {
  int bn = blockIdx.x, bm = blockIdx.y;
  const u16 *bh, *bl; float* C; int N, bc;
  if (bn < 16)      { bh = WqTh; bl = WqTl; C = q; N = 2048; bc = bn; }
  else if (bn < 18) { bh = WkTh; bl = WkTl; C = k; N = 256;  bc = bn - 16; }
  else              { bh = WvTh; bl = WvTl; C = v; N = 256;  bc = bn - 18; }
  mfma_gemm_body(hsH, hsL, bh, bl, C, N, D_, bm, bc);
}

__global__ __launch_bounds__(256)
void mfma_gemm(const u16* __restrict__ Ah, const u16* __restrict__ Al,
               const u16* __restrict__ Bh, const u16* __restrict__ Bl,
               float* __restrict__ C, int N, int K) {
  mfma_gemm_body(Ah, Al, Bh, Bl, C, N, K, blockIdx.y, blockIdx.x);
}

// ---------------------------------------------------------------------------
// In-place RoPE on (B,L,heads,HD): pair (d, d+128) per thread.
// ---------------------------------------------------------------------------
__global__ __launch_bounds__(256)
void rope_kernel(float* __restrict__ x, const float* __restrict__ cosb,
                 const float* __restrict__ sinb, int heads) {
  int idx = blockIdx.x * 256 + threadIdx.x;        // over B*L*heads*128
  int d = idx & 127;
  int rest = idx >> 7;
  int h = rest % heads;
  int bl = rest / heads;                           // b*L + l
  int l = bl & (L_ - 1);
  size_t base = ((size_t)bl * heads + h) * HD_;
  float c = cosb[l * 128 + d], s = sinb[l * 128 + d];
  float x1 = x[base + d], x2 = x[base + 128 + d];
  x[base + d]       = x1 * c - x2 * s;
  x[base + 128 + d] = x1 * s + x2 * c;
}

__device__ __forceinline__ float wave_max64(float v) {
  #pragma unroll
  for (int off = 32; off > 0; off >>= 1) v = fmaxf(v, __shfl_xor(v, off, 64));
  return v;
}
__device__ __forceinline__ float wave_sum64(float v) {
  #pragma unroll
  for (int off = 32; off > 0; off >>= 1) v += __shfl_xor(v, off, 64);
  return v;
}

// ---------------------------------------------------------------------------
// Hedgehog feature map: out[b,h,l,0:64]=exp(p)/Z, [64:128]=exp(-p)/Z.
// One wave handles 4 consecutive l for one (b,h); lane = feature f (0..63).
// ---------------------------------------------------------------------------
__global__ __launch_bounds__(256)
void hedgehog_kernel(const float* __restrict__ x, const float* __restrict__ fm,
                     float* __restrict__ out, int nh_in) {
  __shared__ __align__(16) float rows[4][4][256];
  int wave = threadIdx.x >> 6, lane = threadIdx.x & 63;
  int g = blockIdx.x * 4 + wave;                   // over B*H*(L/4)
  int l4 = g & (L_/4 - 1);
  int bh = g / (L_/4);
  int h = bh & 7, b = bh >> 3;
  int l0 = l4 * 4;
  size_t rstride = (nh_in == 1) ? (size_t)HD_ : (size_t)H_ * HD_;
  const float* xrow = (nh_in == 1)
      ? x + (size_t)(b * L_ + l0) * HD_
      : x + ((size_t)(b * L_ + l0) * H_ + h) * HD_;
  #pragma unroll
  for (int r = 0; r < 4; ++r)
    *(float4*)&rows[wave][r][lane * 4] = *(const float4*)(xrow + r * rstride + lane * 4);
  __syncthreads();

  const float* fmh = fm + (size_t)h * HD_ * FD_;
  float p0 = 0.f, p1 = 0.f, p2 = 0.f, p3 = 0.f;
  for (int dd = 0; dd < HD_; dd += 4) {
    float w0 = fmh[(dd + 0) * FD_ + lane];
    float w1 = fmh[(dd + 1) * FD_ + lane];
    float w2 = fmh[(dd + 2) * FD_ + lane];
    float w3 = fmh[(dd + 3) * FD_ + lane];
    float4 r0 = *(const float4*)&rows[wave][0][dd];
    float4 r1 = *(const float4*)&rows[wave][1][dd];
    float4 r2 = *(const float4*)&rows[wave][2][dd];
    float4 r3 = *(const float4*)&rows[wave][3][dd];
    p0 += r0.x * w0 + r0.y * w1 + r0.z * w2 + r0.w * w3;
    p1 += r1.x * w0 + r1.y * w1 + r1.z * w2 + r1.w * w3;
    p2 += r2.x * w0 + r2.y * w1 + r2.z * w2 + r2.w * w3;
    p3 += r3.x * w0 + r3.y * w1 + r3.z * w2 + r3.w * w3;
  }
  float p[4] = {p0, p1, p2, p3};
  #pragma unroll
  for (int r = 0; r < 4; ++r) {
    float m = wave_max64(fabsf(p[r]));             // max over concat([p,-p])
    float e1 = __expf(p[r] - m);
    float e2 = __expf(-p[r] - m);
    float z = wave_sum64(e1 + e2);
    float inv = 1.0f / z;
    size_t base = ((size_t)bh * L_ + l0 + r) * F_;
    out[base + lane]      = e1 * inv;
    out[base + 64 + lane] = e2 * inv;
  }
}

// ---------------------------------------------------------------------------
// Phase A: per-chunk kv_n[f][d] = sum_{j in chunk} kf[j][f] * v[j][d]
// ---------------------------------------------------------------------------
__global__ __launch_bounds__(256)
void chunk_kv_kernel(const float* __restrict__ kf, const float* __restrict__ v,
                     float* __restrict__ kvc) {
  __shared__ __align__(16) float kfs[64][128];
  int n = blockIdx.x & (NC_ - 1), bh = blockIdx.x >> 5;
  int b = bh >> 3;
  const float* kfp = kf + ((size_t)bh * L_ + (size_t)n * 64) * F_;
  int t = threadIdx.x;
  #pragma unroll
  for (int it = 0; it < 8; ++it) {
    int flat = t * 4 + it * 1024;
    *(float4*)&kfs[flat >> 7][flat & 127] = *(const float4*)(kfp + flat);
  }
  __syncthreads();
  int dg = t & 63;                   // d = dg*4
  int fg = t >> 6;                   // 0..3
  const float* vp = v + (size_t)(b * L_ + n * 64) * HD_ + dg * 4;
  float* outp = kvc + (size_t)blockIdx.x * (F_ * HD_) + dg * 4;
  #pragma unroll
  for (int pass = 0; pass < 4; ++pass) {
    int f0 = fg * 8 + pass * 32;
    float4 acc[8];
    #pragma unroll
    for (int i = 0; i < 8; ++i) acc[i] = make_float4(0.f, 0.f, 0.f, 0.f);
    for (int j = 0; j < 64; ++j) {
      float4 vv = *(const float4*)(vp + (size_t)j * HD_);
      float4 ka = *(const float4*)&kfs[j][f0];
      float4 kb = *(const float4*)&kfs[j][f0 + 4];
      FMA4(acc[0], ka.x, vv); FMA4(acc[1], ka.y, vv);
      FMA4(acc[2], ka.z, vv); FMA4(acc[3], ka.w, vv);
      FMA4(acc[4], kb.x, vv); FMA4(acc[5], kb.y, vv);
      FMA4(acc[6], kb.z, vv); FMA4(acc[7], kb.w, vv);
    }
    #pragma unroll
    for (int ff = 0; ff < 8; ++ff)
      *(float4*)(outp + (size_t)(f0 + ff) * HD_) = acc[ff];
  }
}

// Phase B: exclusive prefix-sum over the 32 chunks, per (b,h,f,d) column.
__global__ __launch_bounds__(256)
void chunk_scan_kernel(float* __restrict__ kvc) {
  size_t c = (size_t)blockIdx.x * 256 + threadIdx.x;   // over B*H * 32768
  size_t bh = c >> 15;
  size_t fd = c & 32767;
  float* p = kvc + bh * ((size_t)NC_ * F_ * HD_) + fd;
  float run = 0.f;
  #pragma unroll
  for (int n = 0; n < NC_; ++n) {
    float val = p[(size_t)n * (F_ * HD_)];
    p[(size_t)n * (F_ * HD_)] = run;
    run += val;
  }
}

// ---------------------------------------------------------------------------
// Phase C: out[i][d] = qs[i]·kv_cum[:,d] + sum_{j<=i} (qs[i]·kf[j]) v[j][d]
// ---------------------------------------------------------------------------
__global__ __launch_bounds__(512)
void chunk_attn_kernel(const float* __restrict__ qf, const float* __restrict__ kf,
                       const float* __restrict__ v, const float* __restrict__ kvc,
                       float* __restrict__ o) {
  __shared__ __align__(16) float qsT[128][68];   // [f][i], scaled q features
  __shared__ __align__(16) float ksT[128][68];   // [f][j]
  __shared__ __align__(16) float ssT[64][68];    // [j][i], masked scores
  int n = blockIdx.x & (NC_ - 1), bh = blockIdx.x >> 5;
  int h = bh & 7, b = bh >> 3;
  int t = threadIdx.x;
  const float* qp = qf + ((size_t)bh * L_ + (size_t)n * 64) * F_;
  const float* kp = kf + ((size_t)bh * L_ + (size_t)n * 64) * F_;
  #pragma unroll
  for (int it = 0; it < 4; ++it) {
    int flat = t * 4 + it * 2048;                // 8192 elems per matrix
    int j = flat >> 7, f = flat & 127;
    float4 qv = *(const float4*)(qp + flat);
    qsT[f + 0][j] = qv.x * SCALE_Q; qsT[f + 1][j] = qv.y * SCALE_Q;
    qsT[f + 2][j] = qv.z * SCALE_Q; qsT[f + 3][j] = qv.w * SCALE_Q;
    float4 kv_ = *(const float4*)(kp + flat);
    ksT[f + 0][j] = kv_.x; ksT[f + 1][j] = kv_.y;
    ksT[f + 2][j] = kv_.z; ksT[f + 3][j] = kv_.w;
  }
  __syncthreads();

  if (t < 256) {
    int j4 = (t & 15) * 4, i4 = (t >> 4) * 4;
    float4 accs[4];
    #pragma unroll
    for (int i = 0; i < 4; ++i) accs[i] = make_float4(0.f, 0.f, 0.f, 0.f);
    for (int f = 0; f < F_; ++f) {
      float4 a4 = *(const float4*)&qsT[f][i4];
      float4 b4 = *(const float4*)&ksT[f][j4];
      FMA4(accs[0], a4.x, b4); FMA4(accs[1], a4.y, b4);
      FMA4(accs[2], a4.z, b4); FMA4(accs[3], a4.w, b4);
    }
    #pragma unroll
    for (int ii = 0; ii < 4; ++ii) {
      float sv[4] = {accs[ii].x, accs[ii].y, accs[ii].z, accs[ii].w};
      #pragma unroll
      for (int jj = 0; jj < 4; ++jj) {
        int i = i4 + ii, j = j4 + jj;
        ssT[j][i] = (j <= i) ? sv[jj] : 0.f;     // causal mask (diag kept)
      }
    }
  }
  __syncthreads();

  int dg = t & 31, ig = t >> 5;                  // ig 0..15
  int i4 = ig * 4;
  const float* kvp = kvc + (size_t)blockIdx.x * (F_ * HD_);
  const float* vp = v + (size_t)(b * L_ + n * 64) * HD_;
  float* op = o + ((size_t)(b * L_ + n * 64) * H_ + h) * HD_;
  #pragma unroll
  for (int pass = 0; pass < 2; ++pass) {
    int d0 = dg * 4 + pass * 128;
    float4 acc[4];
    #pragma unroll
    for (int i = 0; i < 4; ++i) acc[i] = make_float4(0.f, 0.f, 0.f, 0.f);
    for (int f = 0; f < F_; ++f) {               // inter-chunk: qs @ kv_cum
      float4 kvv = *(const float4*)(kvp + (size_t)f * HD_ + d0);
      float4 a4 = *(const float4*)&qsT[f][i4];
      FMA4(acc[0], a4.x, kvv); FMA4(acc[1], a4.y, kvv);
      FMA4(acc[2], a4.z, kvv); FMA4(acc[3], a4.w, kvv);
    }
    for (int j = 0; j < 64; ++j) {               // intra-chunk: s @ v
      float4 vv = *(const float4*)(vp + (size_t)j * HD_ + d0);
      float4 s4 = *(const float4*)&ssT[j][i4];
      FMA4(acc[0], s4.x, vv); FMA4(acc[1], s4.y, vv);
      FMA4(acc[2], s4.z, vv); FMA4(acc[3], s4.w, vv);
    }
    #pragma unroll
    for (int ii = 0; ii < 4; ++ii)
      *(float4*)(op + (size_t)(i4 + ii) * (H_ * HD_) + d0) = acc[ii];
  }
}

// ---------------------------------------------------------------------------
extern "C" void kernel_launch(void* const* d_in, const int* in_sizes, int n_in,
                              void* d_out, int out_size, void* d_ws, size_t ws_size,
                              hipStream_t stream) {
  const float* hs   = (const float*)d_in[0];
  const float* fcos = (const float*)d_in[1];
  const float* fsin = (const float*)d_in[2];
  // d_in[3] = mask (all ones, unused)
  const float* Wq  = (const float*)d_in[4];
  const float* Wk  = (const float*)d_in[5];
  const float* Wv  = (const float*)d_in[6];
  const float* Wo  = (const float*)d_in[7];
  const float* fmq = (const float*)d_in[8];
  const float* fmk = (const float*)d_in[9];
  float* out = (float*)d_out;

  float* ws = (float*)d_ws;
  float* q  = ws;                                   // M*2048 (reused as o)
  float* k  = q  + (size_t)M_ * 2048;               // M*256
  float* v  = k  + (size_t)M_ * 256;                // M*256
  float* qf = v  + (size_t)M_ * 256;                // B*H*L*128
  float* kf = qf + (size_t)B_ * H_ * L_ * F_;       // B*H*L*128
  float* kv = kf + (size_t)B_ * H_ * L_ * F_;       // B*H*NC*128*256 (16.8M floats)

  // bf16 scratch aliased into kv (lifetime: before chunk_kv writes kv)
  u16* hsH  = (u16*)kv;                 // 8,388,608
  u16* hsL  = hsH + (size_t)M_ * D_;
  u16* WqTh = hsL + (size_t)M_ * D_;    // 4,194,304
  u16* WqTl = WqTh + (size_t)D_ * 2048;
  u16* WkTh = WqTl + (size_t)D_ * 2048; // 524,288
  u16* WkTl = WkTh + (size_t)D_ * 256;
  u16* WvTh = WkTl + (size_t)D_ * 256;
  u16* WvTl = WvTh + (size_t)D_ * 256;
  // bf16 scratch for final GEMM (after chunk_attn: kv and qf/kf are dead)
  u16* WoTh = (u16*)kv;                 // 4,194,304
  u16* WoTl = WoTh + (size_t)2048 * D_;
  u16* oH   = (u16*)qf;                 // 8,388,608
  u16* oL   = oH + (size_t)M_ * 2048;

  // 1) Pre-split inputs + pre-transposed/split weights
  transpose_split<<<dim3(2048/32, 2048/32), 256, 0, stream>>>(Wq, WqTh, WqTl, D_, 2048);
  transpose_split<<<dim3(256/32,  2048/32), 256, 0, stream>>>(Wk, WkTh, WkTl, D_, 256);
  transpose_split<<<dim3(256/32,  2048/32), 256, 0, stream>>>(Wv, WvTh, WvTl, D_, 256);
  split_kernel<<<((size_t)M_ * D_) / 1024, 256, 0, stream>>>(hs, hsH, hsL);
  // 2) QKV projections via split-bf16 MFMA
  mfma_qkv<<<dim3(20, 32), 256, 0, stream>>>(hsH, hsL, WqTh, WqTl, WkTh, WkTl,
                                             WvTh, WvTl, q, k, v);
  // 3) RoPE in place
  rope_kernel<<<(M_ * H_ * 128) / 256, 256, 0, stream>>>(q, fcos, fsin, H_);
  rope_kernel<<<(M_ * 1 * 128) / 256, 256, 0, stream>>>(k, fcos, fsin, 1);
  // 4) Hedgehog feature maps
  hedgehog_kernel<<<(B_ * H_ * L_) / 16, 256, 0, stream>>>(q, fmq, qf, H_);
  hedgehog_kernel<<<(B_ * H_ * L_) / 16, 256, 0, stream>>>(k, fmk, kf, 1);
  // 5) Per-chunk k^T v outer products, exclusive scan over chunks
  chunk_kv_kernel<<<B_ * H_ * NC_, 256, 0, stream>>>(kf, v, kv);
  chunk_scan_kernel<<<(B_ * H_ * F_ * HD_) / 256, 256, 0, stream>>>(kv);
  // 6) inter + intra chunk attention -> o (reuses q buffer)
  chunk_attn_kernel<<<B_ * H_ * NC_, 512, 0, stream>>>(qf, kf, v, kv, q);
  // 7) Output projection via split-bf16 MFMA (scratch reuses kv/qf space)
  transpose_split<<<dim3(2048/32, 2048/32), 256, 0, stream>>>(Wo, WoTh, WoTl, 2048, D_);
  split_kernel<<<((size_t)M_ * 2048) / 1024, 256, 0, stream>>>(q, oH, oL);
  mfma_gemm<<<dim3(16, 32), 256, 0, stream>>>(oH, oL, WoTh, WoTl, out, D_, 2048);
}

// Round 3
// 627.048 us; speedup vs baseline: 1.9624x; 1.0438x over previous
//
#include <hip/hip_runtime.h>

#define B_ 2
#define L_ 2048
#define D_ 2048
#define H_ 8
#define HD_ 256
#define FD_ 64
#define F_ 128          // 2*FD
#define NC_ 32          // L/CHUNK
#define M_ (B_*L_)      // 4096
#define SCALE_Q 0.08838834764831845f   // 128^-0.5

typedef unsigned short u16;
typedef __attribute__((ext_vector_type(8))) short bf16x8;
typedef __attribute__((ext_vector_type(4))) float f32x4;

#define FMA4(a_, s_, v_) { (a_).x += (s_)*(v_).x; (a_).y += (s_)*(v_).y; \
                           (a_).z += (s_)*(v_).z; (a_).w += (s_)*(v_).w; }

// ---------------------------------------------------------------------------
// bf16 split helpers (round-to-nearest-even)
// ---------------------------------------------------------------------------
__device__ __forceinline__ u16 bf16_rne(float x) {
  unsigned u = __float_as_uint(x);
  return (u16)((u + 0x7fffu + ((u >> 16) & 1u)) >> 16);
}
__device__ __forceinline__ void bf16_split(float x, u16& h, u16& l) {
  unsigned u = __float_as_uint(x);
  unsigned hb = (u + 0x7fffu + ((u >> 16) & 1u)) >> 16;
  h = (u16)hb;
  float hf = __uint_as_float(hb << 16);
  l = bf16_rne(x - hf);
}

// async global->LDS, 16B per lane, wave-uniform LDS base + 16*lane
__device__ __forceinline__ void gl_lds16(const u16* g, u16* l) {
  __builtin_amdgcn_global_load_lds(
      (const __attribute__((address_space(1))) unsigned int*)g,
      (__attribute__((address_space(3))) unsigned int*)l, 16, 0, 0);
}

// Split a contiguous fp32 array into bf16 hi/lo arrays. 4 elems/thread.
__global__ __launch_bounds__(256)
void split_kernel(const float* __restrict__ x, u16* __restrict__ h,
                  u16* __restrict__ l) {
  int i = (blockIdx.x * 256 + threadIdx.x) * 4;
  float4 vv = *(const float4*)(x + i);
  ushort4 hv, lv;
  bf16_split(vv.x, hv.x, lv.x);
  bf16_split(vv.y, hv.y, lv.y);
  bf16_split(vv.z, hv.z, lv.z);
  bf16_split(vv.w, hv.w, lv.w);
  *(ushort4*)(h + i) = hv;
  *(ushort4*)(l + i) = lv;
}

// Transpose W[K][N] -> T[N][K] with bf16 hi/lo split. 32x32 tiles.
__global__ __launch_bounds__(256)
void transpose_split(const float* __restrict__ W, u16* __restrict__ Th,
                     u16* __restrict__ Tl, int K, int N) {
  __shared__ float tile[32][33];
  int n0 = blockIdx.x * 32, k0 = blockIdx.y * 32;
  int tx = threadIdx.x & 31, ty = threadIdx.x >> 5;   // ty 0..7
  #pragma unroll
  for (int i = 0; i < 4; ++i)
    tile[ty + i * 8][tx] = W[(size_t)(k0 + ty + i * 8) * N + n0 + tx];
  __syncthreads();
  #pragma unroll
  for (int i = 0; i < 4; ++i) {
    float x = tile[tx][ty + i * 8];     // W[k0+tx][n0+ty+i*8]
    u16 hb, lb; bf16_split(x, hb, lb);
    size_t idx = (size_t)(n0 + ty + i * 8) * K + k0 + tx;
    Th[idx] = hb; Tl[idx] = lb;
  }
}

// ---------------------------------------------------------------------------
// Split-bf16 MFMA GEMM: C(fp32) = (Ah+Al)(Bh+Bl) ~= AhBh + AhBl + AlBh
// A: [M][K] row-major bf16-bits; B: B^T [N][K] row-major bf16-bits.
// 128x128 tile, BK=32, 256 threads (4 waves, each 64x64 = 4x4 MFMA tiles).
// Staging via global_load_lds (16B/lane) into UNPADDED [128][32] u16 tiles;
// chunk index XOR-swizzled at the GLOBAL address (slot cs holds chunk
// cs ^ ((row>>1)&3)) so both the fixed contiguous LDS writes and the
// ds_read_b128 fragment reads are bank-conflict-free.
// ---------------------------------------------------------------------------
__device__ __forceinline__ void mfma_gemm_body(
    const u16* __restrict__ Ah, const u16* __restrict__ Al,
    const u16* __restrict__ Bh, const u16* __restrict__ Bl,
    float* __restrict__ C, int N, int K, int bm, int bn) {
  __shared__ __align__(16) u16 Ahs[128][32];
  __shared__ __align__(16) u16 Als[128][32];
  __shared__ __align__(16) u16 Bhs[128][32];
  __shared__ __align__(16) u16 Bls[128][32];
  const int t = threadIdx.x;
  const int lane = t & 63, wave = t >> 6;
  const int wm = wave >> 1, wn = wave & 1;
  const int fr = lane & 15, g = lane >> 4;
  const int col = (g ^ ((fr >> 1) & 3)) * 8;     // swizzled k-chunk slot

  const u16* Ahp = Ah + (size_t)(bm * 128) * K;
  const u16* Alp = Al + (size_t)(bm * 128) * K;
  const u16* Bhp = Bh + (size_t)(bn * 128) * K;
  const u16* Blp = Bl + (size_t)(bn * 128) * K;

  // staging slots: call c covers LDS u16 [(wave*2+c)*512, +512); this lane's
  // slot j -> row j>>2, slot-chunk j&3, source chunk (j&3)^((j>>3)&3).
  int j0 = (wave * 2 + 0) * 64 + lane;
  int j1 = (wave * 2 + 1) * 64 + lane;
  const size_t go0 = (size_t)(j0 >> 2) * K + ((j0 & 3) ^ ((j0 >> 3) & 3)) * 8;
  const size_t go1 = (size_t)(j1 >> 2) * K + ((j1 & 3) ^ ((j1 >> 3) & 3)) * 8;
  u16* lA0 = &Ahs[0][0] + (wave * 2 + 0) * 512;
  u16* lA1 = &Ahs[0][0] + (wave * 2 + 1) * 512;
  u16* lL0 = &Als[0][0] + (wave * 2 + 0) * 512;
  u16* lL1 = &Als[0][0] + (wave * 2 + 1) * 512;
  u16* lB0 = &Bhs[0][0] + (wave * 2 + 0) * 512;
  u16* lB1 = &Bhs[0][0] + (wave * 2 + 1) * 512;
  u16* lM0 = &Bls[0][0] + (wave * 2 + 0) * 512;
  u16* lM1 = &Bls[0][0] + (wave * 2 + 1) * 512;

  f32x4 acc[4][4];
  #pragma unroll
  for (int a = 0; a < 4; ++a)
    #pragma unroll
    for (int b2 = 0; b2 < 4; ++b2) acc[a][b2] = {0.f, 0.f, 0.f, 0.f};

  for (int k0 = 0; k0 < K; k0 += 32) {
    __syncthreads();                              // LDS free from prev iter
    gl_lds16(Ahp + go0 + k0, lA0);
    gl_lds16(Ahp + go1 + k0, lA1);
    gl_lds16(Alp + go0 + k0, lL0);
    gl_lds16(Alp + go1 + k0, lL1);
    gl_lds16(Bhp + go0 + k0, lB0);
    gl_lds16(Bhp + go1 + k0, lB1);
    gl_lds16(Blp + go0 + k0, lM0);
    gl_lds16(Blp + go1 + k0, lM1);
    __syncthreads();                              // vmcnt drained by compiler

    bf16x8 fa[4], fb[4], fx[4];
    #pragma unroll
    for (int mt = 0; mt < 4; ++mt)
      fa[mt] = *(const bf16x8*)&Ahs[wm * 64 + mt * 16 + fr][col];
    #pragma unroll
    for (int nt = 0; nt < 4; ++nt)
      fb[nt] = *(const bf16x8*)&Bhs[wn * 64 + nt * 16 + fr][col];
    #pragma unroll
    for (int mt = 0; mt < 4; ++mt)
      #pragma unroll
      for (int nt = 0; nt < 4; ++nt)
        acc[mt][nt] = __builtin_amdgcn_mfma_f32_16x16x32_bf16(fa[mt], fb[nt], acc[mt][nt], 0, 0, 0);
    #pragma unroll
    for (int nt = 0; nt < 4; ++nt)
      fx[nt] = *(const bf16x8*)&Bls[wn * 64 + nt * 16 + fr][col];
    #pragma unroll
    for (int mt = 0; mt < 4; ++mt)
      #pragma unroll
      for (int nt = 0; nt < 4; ++nt)
        acc[mt][nt] = __builtin_amdgcn_mfma_f32_16x16x32_bf16(fa[mt], fx[nt], acc[mt][nt], 0, 0, 0);
    #pragma unroll
    for (int mt = 0; mt < 4; ++mt)
      fa[mt] = *(const bf16x8*)&Als[wm * 64 + mt * 16 + fr][col];
    #pragma unroll
    for (int mt = 0; mt < 4; ++mt)
      #pragma unroll
      for (int nt = 0; nt < 4; ++nt)
        acc[mt][nt] = __builtin_amdgcn_mfma_f32_16x16x32_bf16(fa[mt], fb[nt], acc[mt][nt], 0, 0, 0);
  }

  // Epilogue: C/D layout col=lane&15, row=(lane>>4)*4+i
  float* Cp = C + (size_t)(bm * 128 + wm * 64) * N + bn * 128 + wn * 64;
  const int rq = (lane >> 4) * 4;
  #pragma unroll
  for (int mt = 0; mt < 4; ++mt)
    #pragma unroll
    for (int nt = 0; nt < 4; ++nt) {
      #pragma unroll
      for (int i = 0; i < 4; ++i)
        Cp[(size_t)(mt * 16 + rq + i) * N + nt * 16 + fr] = acc[mt][nt][i];
    }
}

__global__ __launch_bounds__(256)
void mfma_qkv(const u16* __restrict__ hsH, const u16* __restrict__ hsL,
              const u16* __restrict__ WqTh, const u16* __restrict__ WqTl,
              const u16* __restrict__ WkTh, const u16* __restrict__ WkTl,
              const u16* __restrict__ WvTh, const u16* __restrict__ WvTl,
              float* __restrict__ q, float* __restrict__ k, float* __restrict__ v) {
  int bn = blockIdx.x, bm = blockIdx.y;
  const u16 *bh, *bl; float* C; int N, bc;
  if (bn < 16)      { bh = WqTh; bl = WqTl; C = q; N = 2048; bc = bn; }
  else if (bn < 18) { bh = WkTh; bl = WkTl; C = k; N = 256;  bc = bn - 16; }
  else              { bh = WvTh; bl = WvTl; C = v; N = 256;  bc = bn - 18; }
  mfma_gemm_body(hsH, hsL, bh, bl, C, N, D_, bm, bc);
}

__global__ __launch_bounds__(256)
void mfma_gemm(const u16* __restrict__ Ah, const u16* __restrict__ Al,
               const u16* __restrict__ Bh, const u16* __restrict__ Bl,
               float* __restrict__ C, int N, int K) {
  mfma_gemm_body(Ah, Al, Bh, Bl, C, N, K, blockIdx.y, blockIdx.x);
}

__device__ __forceinline__ float wave_max64(float v) {
  #pragma unroll
  for (int off = 32; off > 0; off >>= 1) v = fmaxf(v, __shfl_xor(v, off, 64));
  return v;
}
__device__ __forceinline__ float wave_sum64(float v) {
  #pragma unroll
  for (int off = 32; off > 0; off >>= 1) v += __shfl_xor(v, off, 64);
  return v;
}

// ---------------------------------------------------------------------------
// Fused RoPE + hedgehog feature map.
// Input x is the raw (un-roped) projection; rope applied in-register via
// partner-lane shuffle (lanes 0..31 hold d<128, 32..63 hold d>=128).
// out[b,h,l,0:64]=exp(p)/Z, [64:128]=exp(-p)/Z.
// One wave handles 4 consecutive l for one (b,h); lane = feature f (0..63).
// ---------------------------------------------------------------------------
__global__ __launch_bounds__(256)
void hedgehog_kernel(const float* __restrict__ x, const float* __restrict__ fm,
                     const float* __restrict__ cosb, const float* __restrict__ sinb,
                     float* __restrict__ out, int nh_in) {
  __shared__ __align__(16) float rows[4][4][256];
  int wave = threadIdx.x >> 6, lane = threadIdx.x & 63;
  int g = blockIdx.x * 4 + wave;                   // over B*H*(L/4)
  int l4 = g & (L_/4 - 1);
  int bh = g / (L_/4);
  int h = bh & 7, b = bh >> 3;
  int l0 = l4 * 4;
  size_t rstride = (nh_in == 1) ? (size_t)HD_ : (size_t)H_ * HD_;
  const float* xrow = (nh_in == 1)
      ? x + (size_t)(b * L_ + l0) * HD_
      : x + ((size_t)(b * L_ + l0) * H_ + h) * HD_;
  int dd = (lane & 31) * 4;                        // rope pair index base
  #pragma unroll
  for (int r = 0; r < 4; ++r) {
    float4 v = *(const float4*)(xrow + r * rstride + lane * 4);
    float4 u;
    u.x = __shfl_xor(v.x, 32, 64); u.y = __shfl_xor(v.y, 32, 64);
    u.z = __shfl_xor(v.z, 32, 64); u.w = __shfl_xor(v.w, 32, 64);
    int l = l0 + r;
    float4 c = *(const float4*)(cosb + (size_t)l * 128 + dd);
    float4 s = *(const float4*)(sinb + (size_t)l * 128 + dd);
    float4 ro;
    if (lane < 32) {       // x1=v, x2=u : x1*c - x2*s
      ro.x = v.x * c.x - u.x * s.x; ro.y = v.y * c.y - u.y * s.y;
      ro.z = v.z * c.z - u.z * s.z; ro.w = v.w * c.w - u.w * s.w;
    } else {               // x1=u, x2=v : x1*s + x2*c
      ro.x = u.x * s.x + v.x * c.x; ro.y = u.y * s.y + v.y * c.y;
      ro.z = u.z * s.z + v.z * c.z; ro.w = u.w * s.w + v.w * c.w;
    }
    *(float4*)&rows[wave][r][lane * 4] = ro;
  }
  __syncthreads();

  const float* fmh = fm + (size_t)h * HD_ * FD_;
  float p0 = 0.f, p1 = 0.f, p2 = 0.f, p3 = 0.f;
  for (int d2 = 0; d2 < HD_; d2 += 4) {
    float w0 = fmh[(d2 + 0) * FD_ + lane];
    float w1 = fmh[(d2 + 1) * FD_ + lane];
    float w2 = fmh[(d2 + 2) * FD_ + lane];
    float w3 = fmh[(d2 + 3) * FD_ + lane];
    float4 r0 = *(const float4*)&rows[wave][0][d2];
    float4 r1 = *(const float4*)&rows[wave][1][d2];
    float4 r2 = *(const float4*)&rows[wave][2][d2];
    float4 r3 = *(const float4*)&rows[wave][3][d2];
    p0 += r0.x * w0 + r0.y * w1 + r0.z * w2 + r0.w * w3;
    p1 += r1.x * w0 + r1.y * w1 + r1.z * w2 + r1.w * w3;
    p2 += r2.x * w0 + r2.y * w1 + r2.z * w2 + r2.w * w3;
    p3 += r3.x * w0 + r3.y * w1 + r3.z * w2 + r3.w * w3;
  }
  float p[4] = {p0, p1, p2, p3};
  #pragma unroll
  for (int r = 0; r < 4; ++r) {
    float m = wave_max64(fabsf(p[r]));             // max over concat([p,-p])
    float e1 = __expf(p[r] - m);
    float e2 = __expf(-p[r] - m);
    float z = wave_sum64(e1 + e2);
    float inv = 1.0f / z;
    size_t base = ((size_t)bh * L_ + l0 + r) * F_;
    out[base + lane]      = e1 * inv;
    out[base + 64 + lane] = e2 * inv;
  }
}

// ---------------------------------------------------------------------------
// Phase A: per-chunk kv_n[f][d] = sum_{j in chunk} kf[j][f] * v[j][d]
// ---------------------------------------------------------------------------
__global__ __launch_bounds__(256)
void chunk_kv_kernel(const float* __restrict__ kf, const float* __restrict__ v,
                     float* __restrict__ kvc) {
  __shared__ __align__(16) float kfs[64][128];
  int n = blockIdx.x & (NC_ - 1), bh = blockIdx.x >> 5;
  int b = bh >> 3;
  const float* kfp = kf + ((size_t)bh * L_ + (size_t)n * 64) * F_;
  int t = threadIdx.x;
  #pragma unroll
  for (int it = 0; it < 8; ++it) {
    int flat = t * 4 + it * 1024;
    *(float4*)&kfs[flat >> 7][flat & 127] = *(const float4*)(kfp + flat);
  }
  __syncthreads();
  int dg = t & 63;                   // d = dg*4
  int fg = t >> 6;                   // 0..3
  const float* vp = v + (size_t)(b * L_ + n * 64) * HD_ + dg * 4;
  float* outp = kvc + (size_t)blockIdx.x * (F_ * HD_) + dg * 4;
  #pragma unroll
  for (int pass = 0; pass < 4; ++pass) {
    int f0 = fg * 8 + pass * 32;
    float4 acc[8];
    #pragma unroll
    for (int i = 0; i < 8; ++i) acc[i] = make_float4(0.f, 0.f, 0.f, 0.f);
    for (int j = 0; j < 64; ++j) {
      float4 vv = *(const float4*)(vp + (size_t)j * HD_);
      float4 ka = *(const float4*)&kfs[j][f0];
      float4 kb = *(const float4*)&kfs[j][f0 + 4];
      FMA4(acc[0], ka.x, vv); FMA4(acc[1], ka.y, vv);
      FMA4(acc[2], ka.z, vv); FMA4(acc[3], ka.w, vv);
      FMA4(acc[4], kb.x, vv); FMA4(acc[5], kb.y, vv);
      FMA4(acc[6], kb.z, vv); FMA4(acc[7], kb.w, vv);
    }
    #pragma unroll
    for (int ff = 0; ff < 8; ++ff)
      *(float4*)(outp + (size_t)(f0 + ff) * HD_) = acc[ff];
  }
}

// Phase B: exclusive prefix-sum over the 32 chunks, per (b,h,f,d) column.
__global__ __launch_bounds__(256)
void chunk_scan_kernel(float* __restrict__ kvc) {
  size_t c = (size_t)blockIdx.x * 256 + threadIdx.x;   // over B*H * 32768
  size_t bh = c >> 15;
  size_t fd = c & 32767;
  float* p = kvc + bh * ((size_t)NC_ * F_ * HD_) + fd;
  float run = 0.f;
  #pragma unroll
  for (int n = 0; n < NC_; ++n) {
    float val = p[(size_t)n * (F_ * HD_)];
    p[(size_t)n * (F_ * HD_)] = run;
    run += val;
  }
}

// ---------------------------------------------------------------------------
// Phase C: out[i][d] = qs[i]·kv_cum[:,d] + sum_{j<=i} (qs[i]·kf[j]) v[j][d]
// Writes bf16-split oH/oL directly (Wo GEMM A-operand), layout [M][2048].
// ---------------------------------------------------------------------------
__global__ __launch_bounds__(512)
void chunk_attn_kernel(const float* __restrict__ qf, const float* __restrict__ kf,
                       const float* __restrict__ v, const float* __restrict__ kvc,
                       u16* __restrict__ oH, u16* __restrict__ oL) {
  __shared__ __align__(16) float qsT[128][68];   // [f][i], scaled q features
  __shared__ __align__(16) float ksT[128][68];   // [f][j]
  __shared__ __align__(16) float ssT[64][68];    // [j][i], masked scores
  int n = blockIdx.x & (NC_ - 1), bh = blockIdx.x >> 5;
  int h = bh & 7, b = bh >> 3;
  int t = threadIdx.x;
  const float* qp = qf + ((size_t)bh * L_ + (size_t)n * 64) * F_;
  const float* kp = kf + ((size_t)bh * L_ + (size_t)n * 64) * F_;
  #pragma unroll
  for (int it = 0; it < 4; ++it) {
    int flat = t * 4 + it * 2048;                // 8192 elems per matrix
    int j = flat >> 7, f = flat & 127;
    float4 qv = *(const float4*)(qp + flat);
    qsT[f + 0][j] = qv.x * SCALE_Q; qsT[f + 1][j] = qv.y * SCALE_Q;
    qsT[f + 2][j] = qv.z * SCALE_Q; qsT[f + 3][j] = qv.w * SCALE_Q;
    float4 kv_ = *(const float4*)(kp + flat);
    ksT[f + 0][j] = kv_.x; ksT[f + 1][j] = kv_.y;
    ksT[f + 2][j] = kv_.z; ksT[f + 3][j] = kv_.w;
  }
  __syncthreads();

  if (t < 256) {
    int j4 = (t & 15) * 4, i4 = (t >> 4) * 4;
    float4 accs[4];
    #pragma unroll
    for (int i = 0; i < 4; ++i) accs[i] = make_float4(0.f, 0.f, 0.f, 0.f);
    for (int f = 0; f < F_; ++f) {
      float4 a4 = *(const float4*)&qsT[f][i4];
      float4 b4 = *(const float4*)&ksT[f][j4];
      FMA4(accs[0], a4.x, b4); FMA4(accs[1], a4.y, b4);
      FMA4(accs[2], a4.z, b4); FMA4(accs[3], a4.w, b4);
    }
    #pragma unroll
    for (int ii = 0; ii < 4; ++ii) {
      float sv[4] = {accs[ii].x, accs[ii].y, accs[ii].z, accs[ii].w};
      #pragma unroll
      for (int jj = 0; jj < 4; ++jj) {
        int i = i4 + ii, j = j4 + jj;
        ssT[j][i] = (j <= i) ? sv[jj] : 0.f;     // causal mask (diag kept)
      }
    }
  }
  __syncthreads();

  int dg = t & 31, ig = t >> 5;                  // ig 0..15
  int i4 = ig * 4;
  const float* kvp = kvc + (size_t)blockIdx.x * (F_ * HD_);
  const float* vp = v + (size_t)(b * L_ + n * 64) * HD_;
  u16* oHp = oH + (size_t)(b * L_ + n * 64) * 2048 + h * 256;
  u16* oLp = oL + (size_t)(b * L_ + n * 64) * 2048 + h * 256;
  #pragma unroll
  for (int pass = 0; pass < 2; ++pass) {
    int d0 = dg * 4 + pass * 128;
    float4 acc[4];
    #pragma unroll
    for (int i = 0; i < 4; ++i) acc[i] = make_float4(0.f, 0.f, 0.f, 0.f);
    for (int f = 0; f < F_; ++f) {               // inter-chunk: qs @ kv_cum
      float4 kvv = *(const float4*)(kvp + (size_t)f * HD_ + d0);
      float4 a4 = *(const float4*)&qsT[f][i4];
      FMA4(acc[0], a4.x, kvv); FMA4(acc[1], a4.y, kvv);
      FMA4(acc[2], a4.z, kvv); FMA4(acc[3], a4.w, kvv);
    }
    for (int j = 0; j < 64; ++j) {               // intra-chunk: s @ v
      float4 vv = *(const float4*)(vp + (size_t)j * HD_ + d0);
      float4 s4 = *(const float4*)&ssT[j][i4];
      FMA4(acc[0], s4.x, vv); FMA4(acc[1], s4.y, vv);
      FMA4(acc[2], s4.z, vv); FMA4(acc[3], s4.w, vv);
    }
    #pragma unroll
    for (int ii = 0; ii < 4; ++ii) {
      ushort4 hv, lv;
      bf16_split(acc[ii].x, hv.x, lv.x);
      bf16_split(acc[ii].y, hv.y, lv.y);
      bf16_split(acc[ii].z, hv.z, lv.z);
      bf16_split(acc[ii].w, hv.w, lv.w);
      size_t off = (size_t)(i4 + ii) * 2048 + d0;
      *(ushort4*)(oHp + off) = hv;
      *(ushort4*)(oLp + off) = lv;
    }
  }
}

// ---------------------------------------------------------------------------
extern "C" void kernel_launch(void* const* d_in, const int* in_sizes, int n_in,
                              void* d_out, int out_size, void* d_ws, size_t ws_size,
                              hipStream_t stream) {
  const float* hs   = (const float*)d_in[0];
  const float* fcos = (const float*)d_in[1];
  const float* fsin = (const float*)d_in[2];
  // d_in[3] = mask (all ones, unused)
  const float* Wq  = (const float*)d_in[4];
  const float* Wk  = (const float*)d_in[5];
  const float* Wv  = (const float*)d_in[6];
  const float* Wo  = (const float*)d_in[7];
  const float* fmq = (const float*)d_in[8];
  const float* fmk = (const float*)d_in[9];
  float* out = (float*)d_out;

  float* ws = (float*)d_ws;
  float* q  = ws;                                   // M*2048 (later: oH/oL)
  float* k  = q  + (size_t)M_ * 2048;               // M*256
  float* v  = k  + (size_t)M_ * 256;                // M*256
  float* qf = v  + (size_t)M_ * 256;                // B*H*L*128
  float* kf = qf + (size_t)B_ * H_ * L_ * F_;       // B*H*L*128
  float* kv = kf + (size_t)B_ * H_ * L_ * F_;       // B*H*NC*128*256 (16.8M floats)

  // bf16 scratch aliased into kv (lifetime: before chunk_kv writes kv)
  u16* hsH  = (u16*)kv;                 // 8,388,608
  u16* hsL  = hsH + (size_t)M_ * D_;
  u16* WqTh = hsL + (size_t)M_ * D_;    // 4,194,304
  u16* WqTl = WqTh + (size_t)D_ * 2048;
  u16* WkTh = WqTl + (size_t)D_ * 2048; // 524,288
  u16* WkTl = WkTh + (size_t)D_ * 256;
  u16* WvTh = WkTl + (size_t)D_ * 256;
  u16* WvTl = WvTh + (size_t)D_ * 256;
  // bf16 scratch for final GEMM:
  //   oH/oL live in the q region (q dead after hedgehog_q reads it)
  //   WoT lives in the kv region (kv dead after chunk_attn)
  u16* oH   = (u16*)q;                  // 8,388,608 u16
  u16* oL   = oH + (size_t)M_ * 2048;
  u16* WoTh = (u16*)kv;                 // 4,194,304
  u16* WoTl = WoTh + (size_t)2048 * D_;

  // 1) Pre-split inputs + pre-transposed/split weights
  transpose_split<<<dim3(2048/32, 2048/32), 256, 0, stream>>>(Wq, WqTh, WqTl, D_, 2048);
  transpose_split<<<dim3(256/32,  2048/32), 256, 0, stream>>>(Wk, WkTh, WkTl, D_, 256);
  transpose_split<<<dim3(256/32,  2048/32), 256, 0, stream>>>(Wv, WvTh, WvTl, D_, 256);
  split_kernel<<<((size_t)M_ * D_) / 1024, 256, 0, stream>>>(hs, hsH, hsL);
  // 2) QKV projections via split-bf16 MFMA (async LDS staging)
  mfma_qkv<<<dim3(20, 32), 256, 0, stream>>>(hsH, hsL, WqTh, WqTl, WkTh, WkTl,
                                             WvTh, WvTl, q, k, v);
  // 3) Fused RoPE + hedgehog feature maps
  hedgehog_kernel<<<(B_ * H_ * L_) / 16, 256, 0, stream>>>(q, fmq, fcos, fsin, qf, H_);
  hedgehog_kernel<<<(B_ * H_ * L_) / 16, 256, 0, stream>>>(k, fmk, fcos, fsin, kf, 1);
  // 4) Per-chunk k^T v outer products, exclusive scan over chunks
  chunk_kv_kernel<<<B_ * H_ * NC_, 256, 0, stream>>>(kf, v, kv);
  chunk_scan_kernel<<<(B_ * H_ * F_ * HD_) / 256, 256, 0, stream>>>(kv);
  // 5) inter + intra chunk attention -> bf16-split oH/oL (in q region)
  chunk_attn_kernel<<<B_ * H_ * NC_, 512, 0, stream>>>(qf, kf, v, kv, oH, oL);
  // 6) Output projection via split-bf16 MFMA
  transpose_split<<<dim3(2048/32, 2048/32), 256, 0, stream>>>(Wo, WoTh, WoTl, 2048, D_);
  mfma_gemm<<<dim3(16, 32), 256, 0, stream>>>(oH, oL, WoTh, WoTl, out, D_, 2048);
}